// Round 1
// 959.135 us; speedup vs baseline: 2.9622x; 2.9622x over previous
//
#include <hip/hip_runtime.h>
#include <cstdint>
#include <cstddef>

typedef unsigned short u16;
typedef unsigned int u32;
typedef __attribute__((ext_vector_type(8))) short bh8;
typedef __attribute__((ext_vector_type(4))) float fx4;

#define T_TOK 2048
#define D_DIM 1024
#define H_DIM 512
#define N_EXP 64
#define K_TOP 6
#define N_ASG (T_TOK * K_TOP)   // 12288

__device__ __forceinline__ float bf2f(u16 v) {
    union { u32 u; float f; } c; c.u = ((u32)v) << 16; return c.f;
}
__device__ __forceinline__ u16 f2bf(float f) {
    union { u32 u; float f; } c; c.f = f;
    u32 u = c.u;
    return (u16)((u + 0x7fffu + ((u >> 16) & 1u)) >> 16);
}

// ---------------- RMSNorm (f32 in) -> xnb (bf16) ----------------
__global__ __launch_bounds__(256) void rmsnorm_k(
    const float* __restrict__ x, const float* __restrict__ nw, u16* __restrict__ xnb)
{
    int t = blockIdx.x, tid = threadIdx.x;
    int d0 = tid << 2;
    float4 xv = *(const float4*)(x + (size_t)t * D_DIM + d0);
    float ss = xv.x * xv.x + xv.y * xv.y + xv.z * xv.z + xv.w * xv.w;
    #pragma unroll
    for (int o = 32; o > 0; o >>= 1) ss += __shfl_down(ss, o);
    __shared__ float red[4];
    if ((tid & 63) == 0) red[tid >> 6] = ss;
    __syncthreads();
    float ms = (red[0] + red[1] + red[2] + red[3]) * (1.f / (float)D_DIM);
    float sc = rsqrtf(ms + 1.1920929e-07f);
    float4 wv = *(const float4*)(nw + d0);
    ushort4 ob;
    ob.x = f2bf(xv.x * sc * wv.x);
    ob.y = f2bf(xv.y * sc * wv.y);
    ob.z = f2bf(xv.z * sc * wv.z);
    ob.w = f2bf(xv.w * sc * wv.w);
    *(ushort4*)(xnb + (size_t)t * D_DIM + d0) = ob;
}

// ---------------- router with fused fp32 norm: raw[t][e] (all fp32) ----------------
__global__ __launch_bounds__(256) void routernorm_k(
    const float* __restrict__ x, const float* __restrict__ nw,
    const float* __restrict__ Wr, float* __restrict__ raw)
{
    int t = blockIdx.x, tid = threadIdx.x;
    __shared__ float xs[D_DIM];
    __shared__ float ps[256];
    __shared__ float red[4];
    int d0 = tid << 2;
    float4 xv = *(const float4*)(x + (size_t)t * D_DIM + d0);
    float ss = xv.x * xv.x + xv.y * xv.y + xv.z * xv.z + xv.w * xv.w;
    #pragma unroll
    for (int o = 32; o > 0; o >>= 1) ss += __shfl_down(ss, o);
    if ((tid & 63) == 0) red[tid >> 6] = ss;
    __syncthreads();
    float ms = (red[0] + red[1] + red[2] + red[3]) * (1.f / (float)D_DIM);
    float sc = rsqrtf(ms + 1.1920929e-07f);
    float4 wv = *(const float4*)(nw + d0);
    float4 xf;
    xf.x = xv.x * sc * wv.x;
    xf.y = xv.y * sc * wv.y;
    xf.z = xv.z * sc * wv.z;
    xf.w = xv.w * sc * wv.w;
    *(float4*)&xs[d0] = xf;
    __syncthreads();
    int e = tid & 63, part = tid >> 6;
    const float* wr = Wr + (size_t)e * D_DIM + part * 256;
    const float* xp = &xs[part * 256];
    float s = 0.f;
    #pragma unroll 8
    for (int i = 0; i < 256; i += 4) {
        float4 w4 = *(const float4*)(wr + i);
        s += xp[i] * w4.x + xp[i + 1] * w4.y + xp[i + 2] * w4.z + xp[i + 3] * w4.w;
    }
    ps[tid] = s;
    __syncthreads();
    if (part == 0) raw[(size_t)t * N_EXP + e] = ps[e] + ps[64 + e] + ps[128 + e] + ps[192 + e];
}

// ---------------- top-k (one wave per token), fp32 ----------------
__global__ void topk_k(const float* __restrict__ raw, const float* __restrict__ ebias,
                       int* __restrict__ cnt, int* __restrict__ tki, float* __restrict__ tkw)
{
    int t = blockIdx.x, lane = threadIdx.x;
    float r = raw[(size_t)t * N_EXP + lane];
    float cur = r + ebias[lane];
    int selI[K_TOP]; float selR[K_TOP];
    #pragma unroll
    for (int k = 0; k < K_TOP; ++k) {
        float v = cur; int id = lane;
        #pragma unroll
        for (int o = 32; o > 0; o >>= 1) {
            float v2 = __shfl_down(v, o); int i2 = __shfl_down(id, o);
            if (v2 > v || (v2 == v && i2 < id)) { v = v2; id = i2; }
        }
        id = __shfl(id, 0);
        if (lane == id) cur = -3.4e38f;
        selI[k] = id;
        selR[k] = __shfl(r, id);
    }
    float s = 0.f;
    #pragma unroll
    for (int k = 0; k < K_TOP; ++k) s += selR[k];
    if (lane < K_TOP) {
        tki[t * K_TOP + lane] = selI[lane];
        tkw[t * K_TOP + lane] = selR[lane] / s;
        atomicAdd(&cnt[selI[lane]], 1);
    }
}

__global__ void scan_k(const int* __restrict__ cnt, int* __restrict__ offs, int* __restrict__ fill)
{
    if (threadIdx.x == 0) {
        int s = 0;
        for (int e = 0; e < N_EXP; ++e) { offs[e] = s; fill[e] = s; s += cnt[e]; }
        offs[N_EXP] = s;
    }
}

__global__ void fill_k(const int* __restrict__ tki, const float* __restrict__ tkw,
                       int* __restrict__ fill, int* __restrict__ atok, float* __restrict__ aw)
{
    int t = blockIdx.x, lane = threadIdx.x;
    if (lane < K_TOP) {
        int e = tki[t * K_TOP + lane];
        int p = atomicAdd(&fill[e], 1);
        atok[p] = t;
        aw[p] = tkw[t * K_TOP + lane];
    }
}

// ---------------- weight convert+transpose: fp32 [mat][K][N] -> bf16 [mat][N][K] ----------------
// grid: (N/64, K/64, nmat), 256 threads
__global__ __launch_bounds__(256) void convT_k(
    const float* __restrict__ in, u16* __restrict__ out, int K, int N)
{
    int mat = blockIdx.z;
    size_t mo = (size_t)mat * K * N;
    int n0 = blockIdx.x << 6, k0 = blockIdx.y << 6;
    __shared__ u16 t[64][72];
    int tid = threadIdx.x;
    int kr = tid >> 4;            // 0..15
    int c4 = (tid & 15) << 2;     // 0..60 step 4
    #pragma unroll
    for (int rr = 0; rr < 4; ++rr) {
        int k = (rr << 4) + kr;
        float4 v = *(const float4*)(in + mo + (size_t)(k0 + k) * N + n0 + c4);
        t[c4 + 0][k] = f2bf(v.x);
        t[c4 + 1][k] = f2bf(v.y);
        t[c4 + 2][k] = f2bf(v.z);
        t[c4 + 3][k] = f2bf(v.w);
    }
    __syncthreads();
    int nr = tid >> 4;
    int k4 = (tid & 15) << 2;
    #pragma unroll
    for (int rr = 0; rr < 4; ++rr) {
        int n = (rr << 4) + nr;
        ushort4 o;
        o.x = t[n][k4 + 0];
        o.y = t[n][k4 + 1];
        o.z = t[n][k4 + 2];
        o.w = t[n][k4 + 3];
        *(ushort4*)(out + mo + (size_t)(n0 + n) * K + k0 + k4) = o;
    }
}

// ============ fast fused per-expert FFN (pre-transposed bf16 weights) ============
// grid (expert, slab): linear block id % 8 == expert % 8 -> expert->XCD affinity.
// 32-row slab, 256 threads = 4 waves; wave w owns a 128-col panel.
// B-fragments load DIRECTLY from global [N][K] bf16 (16B/lane, L2-resident);
// no inner-loop barriers, no staging, no per-iteration f32->bf16 conversion.
template<int ROUTED>
__global__ __launch_bounds__(256) void moe_ffn2_k(
    const u16* __restrict__ xnb,
    const u16* __restrict__ W1t,   // [E][H=512][D=1024]
    const u16* __restrict__ Wgt,   // [512][512]
    const u16* __restrict__ W2t,   // [E][D=1024][H=512]
    const float* __restrict__ b1b, const float* __restrict__ b2b,
    const int* __restrict__ offs, const int* __restrict__ atok,
    const float* __restrict__ aw, float* __restrict__ accG)
{
    int e = blockIdx.x;
    int start = ROUTED ? offs[e] : 0;
    int end   = ROUTED ? offs[e + 1] : T_TOK;
    int rowBase = start + (blockIdx.y << 5);
    if (rowBase >= end) return;
    int rows = end - rowBase; if (rows > 32) rows = 32;

    __shared__ int   tok[32];
    __shared__ float wt[32];
    __shared__ u16 hA[32 * 520];
    __shared__ u16 hG[32 * 520];

    int tid = threadIdx.x;
    if (tid < 32) {
        int cl = rowBase + tid; if (cl >= end) cl = end - 1;
        tok[tid] = ROUTED ? atok[cl] : cl;
        wt[tid]  = ROUTED ? aw[cl] : 1.0f;
    }
    __syncthreads();

    int w = tid >> 6, lane = tid & 63, quad = lane >> 4, l15 = lane & 15;
    int n0w = w << 7;   // 128-col panel base for H-sized phases

    const u16* W1e = W1t + (size_t)e * (H_DIM * D_DIM);
    const u16* W2e = W2t + (size_t)e * (H_DIM * D_DIM);
    const float* b1 = b1b + e * H_DIM;
    const float* b2 = b2b + e * D_DIM;

    // ---- phase 1: h = xn @ W1 + b1 (K=1024 -> N=512) ----
    {
        const u16* a0p = xnb + (size_t)tok[l15] * D_DIM + (quad << 3);
        const u16* a1p = xnb + (size_t)tok[16 + l15] * D_DIM + (quad << 3);
        const u16* bp  = W1e + (size_t)(n0w + l15) * D_DIM + (quad << 3);
        fx4 ac0[8] = {}, ac1[8] = {};
        for (int kb = 0; kb < D_DIM; kb += 32) {
            bh8 a0 = *(const bh8*)(a0p + kb);
            bh8 a1 = *(const bh8*)(a1p + kb);
            #pragma unroll
            for (int ct = 0; ct < 8; ++ct) {
                bh8 b = *(const bh8*)(bp + ((size_t)ct << 14) + kb);   // ct*16*1024
                ac0[ct] = __builtin_amdgcn_mfma_f32_16x16x32_bf16(a0, b, ac0[ct], 0, 0, 0);
                ac1[ct] = __builtin_amdgcn_mfma_f32_16x16x32_bf16(a1, b, ac1[ct], 0, 0, 0);
            }
        }
        #pragma unroll
        for (int ct = 0; ct < 8; ++ct) {
            int col = n0w + (ct << 4) + l15;
            float bv = b1[col];
            #pragma unroll
            for (int r = 0; r < 4; ++r) {
                int r0 = (quad << 2) + r;
                hA[r0 * 520 + col]        = f2bf(ac0[ct][r] + bv);
                hA[(16 + r0) * 520 + col] = f2bf(ac1[ct][r] + bv);
            }
        }
    }
    __syncthreads();

    // ---- phase 2: hg = h * silu(h @ Wg) (K=512 -> N=512) ----
    {
        const u16* A0 = hA + l15 * 520 + (quad << 3);
        const u16* A1 = hA + (16 + l15) * 520 + (quad << 3);
        const u16* bp = Wgt + (size_t)(n0w + l15) * H_DIM + (quad << 3);
        fx4 ac0[8] = {}, ac1[8] = {};
        for (int kb = 0; kb < H_DIM; kb += 32) {
            bh8 a0 = *(const bh8*)(A0 + kb);
            bh8 a1 = *(const bh8*)(A1 + kb);
            #pragma unroll
            for (int ct = 0; ct < 8; ++ct) {
                bh8 b = *(const bh8*)(bp + ((size_t)ct << 13) + kb);   // ct*16*512
                ac0[ct] = __builtin_amdgcn_mfma_f32_16x16x32_bf16(a0, b, ac0[ct], 0, 0, 0);
                ac1[ct] = __builtin_amdgcn_mfma_f32_16x16x32_bf16(a1, b, ac1[ct], 0, 0, 0);
            }
        }
        #pragma unroll
        for (int ct = 0; ct < 8; ++ct) {
            int col = n0w + (ct << 4) + l15;
            #pragma unroll
            for (int r = 0; r < 4; ++r) {
                int r0 = (quad << 2) + r;
                float g0 = ac0[ct][r];
                float h0 = bf2f(hA[r0 * 520 + col]);
                hG[r0 * 520 + col] = f2bf(h0 * g0 * (1.f / (1.f + __expf(-g0))));
                int r1 = 16 + r0;
                float g1 = ac1[ct][r];
                float h1 = bf2f(hA[r1 * 520 + col]);
                hG[r1 * 520 + col] = f2bf(h1 * g1 * (1.f / (1.f + __expf(-g1))));
            }
        }
    }
    __syncthreads();

    // ---- phase 3: acc[tok] += wt * (hg @ W2 + b2) (K=512 -> N=1024, 2 passes/wave) ----
    #pragma unroll 1
    for (int half = 0; half < 2; ++half) {
        int n0 = (w << 8) + (half << 7);
        const u16* A0 = hG + l15 * 520 + (quad << 3);
        const u16* A1 = hG + (16 + l15) * 520 + (quad << 3);
        const u16* bp = W2e + (size_t)(n0 + l15) * H_DIM + (quad << 3);
        fx4 ac0[8] = {}, ac1[8] = {};
        for (int kb = 0; kb < H_DIM; kb += 32) {
            bh8 a0 = *(const bh8*)(A0 + kb);
            bh8 a1 = *(const bh8*)(A1 + kb);
            #pragma unroll
            for (int ct = 0; ct < 8; ++ct) {
                bh8 b = *(const bh8*)(bp + ((size_t)ct << 13) + kb);
                ac0[ct] = __builtin_amdgcn_mfma_f32_16x16x32_bf16(a0, b, ac0[ct], 0, 0, 0);
                ac1[ct] = __builtin_amdgcn_mfma_f32_16x16x32_bf16(a1, b, ac1[ct], 0, 0, 0);
            }
        }
        #pragma unroll
        for (int ct = 0; ct < 8; ++ct) {
            int col = n0 + (ct << 4) + l15;
            float bv = b2[col];
            #pragma unroll
            for (int r = 0; r < 4; ++r) {
                int r0 = (quad << 2) + r;
                if (r0 < rows)
                    atomicAdd(&accG[(size_t)tok[r0] * D_DIM + col], wt[r0] * (ac0[ct][r] + bv));
                int r1 = 16 + r0;
                if (r1 < rows)
                    atomicAdd(&accG[(size_t)tok[r1] * D_DIM + col], wt[r1] * (ac1[ct][r] + bv));
            }
        }
    }
}

// ============ fallback (previous) fused FFN, used only if workspace too small ============
template<int ROUTED>
__global__ __launch_bounds__(256) void moe_ffn_k(
    const u16* __restrict__ xnb,
    const float* __restrict__ W1b, const float* __restrict__ Wg,
    const float* __restrict__ W2b,
    const float* __restrict__ b1b, const float* __restrict__ b2b,
    const int* __restrict__ offs, const int* __restrict__ atok,
    const float* __restrict__ aw, float* __restrict__ accG)
{
    int e = blockIdx.z;
    int start = ROUTED ? offs[e] : 0;
    int end   = ROUTED ? offs[e + 1] : T_TOK;
    int rowBase = start + (blockIdx.y << 5);
    if (rowBase >= end) return;
    int rows = end - rowBase; if (rows > 32) rows = 32;

    __shared__ int   tok[32];
    __shared__ float wt[32];
    __shared__ u16 hA[32 * 520];
    __shared__ u16 hG[32 * 520];
    __shared__ u16 As[32 * 32];
    __shared__ u16 Bs[64 * 36];

    int tid = threadIdx.x;
    if (tid < 32) {
        int cl = rowBase + tid; if (cl >= end) cl = end - 1;
        tok[tid] = ROUTED ? atok[cl] : cl;
        wt[tid]  = ROUTED ? aw[cl] : 1.0f;
    }
    __syncthreads();

    const float* W1 = W1b + (size_t)e * (D_DIM * H_DIM);
    const float* W2 = W2b + (size_t)e * (D_DIM * H_DIM);
    const float* b1 = b1b + e * H_DIM;
    const float* b2 = b2b + e * D_DIM;

    int w = tid >> 6, lane = tid & 63, quad = lane >> 4, l15 = lane & 15;
    int sr2 = tid >> 3, sc2 = (tid & 7) << 2;

    for (int nc = 0; nc < 8; ++nc) {
        int n0 = nc << 6;
        fx4 a0 = {}; fx4 a1 = {};
        for (int kc = 0; kc < 32; ++kc) {
            int kb = kc << 5;
            int2 av = *(const int2*)(xnb + (size_t)tok[sr2] * D_DIM + kb + sc2);
            const float* cp = W1 + n0 + lane;
            int kx = kb + (w << 3);
            u32 p[4];
            #pragma unroll
            for (int jj = 0; jj < 4; ++jj) {
                u32 lo = f2bf(cp[(size_t)(kx + 2 * jj) * H_DIM]);
                u32 hi = f2bf(cp[(size_t)(kx + 2 * jj + 1) * H_DIM]);
                p[jj] = lo | (hi << 16);
            }
            __syncthreads();
            *(int2*)&As[sr2 * 32 + sc2] = av;
            u16* bsw = &Bs[lane * 36 + (w << 3)];
            uint2 q0; q0.x = p[0]; q0.y = p[1];
            uint2 q1; q1.x = p[2]; q1.y = p[3];
            *(uint2*)bsw = q0;
            *(uint2*)(bsw + 4) = q1;
            __syncthreads();
            bh8 af0 = *(const bh8*)&As[l15 * 32 + (quad << 3)];
            bh8 af1 = *(const bh8*)&As[(16 + l15) * 32 + (quad << 3)];
            const u16* brp = &Bs[((w << 4) + l15) * 36 + (quad << 3)];
            union { bh8 v; uint2 u2[2]; } bf;
            bf.u2[0] = *(const uint2*)brp;
            bf.u2[1] = *(const uint2*)(brp + 4);
            a0 = __builtin_amdgcn_mfma_f32_16x16x32_bf16(af0, bf.v, a0, 0, 0, 0);
            a1 = __builtin_amdgcn_mfma_f32_16x16x32_bf16(af1, bf.v, a1, 0, 0, 0);
        }
        int col = n0 + (w << 4) + l15;
        float bv = b1[col];
        #pragma unroll
        for (int r = 0; r < 4; ++r) {
            hA[((quad << 2) + r) * 520 + col]      = f2bf(a0[r] + bv);
            hA[(16 + (quad << 2) + r) * 520 + col] = f2bf(a1[r] + bv);
        }
    }
    __syncthreads();

    for (int nc = 0; nc < 8; ++nc) {
        int n0 = nc << 6;
        fx4 a0 = {}; fx4 a1 = {};
        for (int kc = 0; kc < 16; ++kc) {
            int kb = kc << 5;
            const float* cp = Wg + n0 + lane;
            int kx = kb + (w << 3);
            u32 p[4];
            #pragma unroll
            for (int jj = 0; jj < 4; ++jj) {
                u32 lo = f2bf(cp[(size_t)(kx + 2 * jj) * H_DIM]);
                u32 hi = f2bf(cp[(size_t)(kx + 2 * jj + 1) * H_DIM]);
                p[jj] = lo | (hi << 16);
            }
            __syncthreads();
            u16* bsw = &Bs[lane * 36 + (w << 3)];
            uint2 q0; q0.x = p[0]; q0.y = p[1];
            uint2 q1; q1.x = p[2]; q1.y = p[3];
            *(uint2*)bsw = q0;
            *(uint2*)(bsw + 4) = q1;
            __syncthreads();
            bh8 af0 = *(const bh8*)&hA[l15 * 520 + kb + (quad << 3)];
            bh8 af1 = *(const bh8*)&hA[(16 + l15) * 520 + kb + (quad << 3)];
            const u16* brp = &Bs[((w << 4) + l15) * 36 + (quad << 3)];
            union { bh8 v; uint2 u2[2]; } bf;
            bf.u2[0] = *(const uint2*)brp;
            bf.u2[1] = *(const uint2*)(brp + 4);
            a0 = __builtin_amdgcn_mfma_f32_16x16x32_bf16(af0, bf.v, a0, 0, 0, 0);
            a1 = __builtin_amdgcn_mfma_f32_16x16x32_bf16(af1, bf.v, a1, 0, 0, 0);
        }
        int col = n0 + (w << 4) + l15;
        #pragma unroll
        for (int r = 0; r < 4; ++r) {
            int r0 = (quad << 2) + r;
            float h0 = bf2f(hA[r0 * 520 + col]);
            float g0 = a0[r];
            hG[r0 * 520 + col] = f2bf(h0 * g0 * (1.f / (1.f + __expf(-g0))));
            int r1 = 16 + r0;
            float h1 = bf2f(hA[r1 * 520 + col]);
            float g1 = a1[r];
            hG[r1 * 520 + col] = f2bf(h1 * g1 * (1.f / (1.f + __expf(-g1))));
        }
    }
    __syncthreads();

    for (int nc = 0; nc < 16; ++nc) {
        int n0 = nc << 6;
        fx4 a0 = {}; fx4 a1 = {};
        for (int kc = 0; kc < 16; ++kc) {
            int kb = kc << 5;
            const float* cp = W2 + n0 + lane;
            int kx = kb + (w << 3);
            u32 p[4];
            #pragma unroll
            for (int jj = 0; jj < 4; ++jj) {
                u32 lo = f2bf(cp[(size_t)(kx + 2 * jj) * D_DIM]);
                u32 hi = f2bf(cp[(size_t)(kx + 2 * jj + 1) * D_DIM]);
                p[jj] = lo | (hi << 16);
            }
            __syncthreads();
            u16* bsw = &Bs[lane * 36 + (w << 3)];
            uint2 q0; q0.x = p[0]; q0.y = p[1];
            uint2 q1; q1.x = p[2]; q1.y = p[3];
            *(uint2*)bsw = q0;
            *(uint2*)(bsw + 4) = q1;
            __syncthreads();
            bh8 af0 = *(const bh8*)&hG[l15 * 520 + kb + (quad << 3)];
            bh8 af1 = *(const bh8*)&hG[(16 + l15) * 520 + kb + (quad << 3)];
            const u16* brp = &Bs[((w << 4) + l15) * 36 + (quad << 3)];
            union { bh8 v; uint2 u2[2]; } bf;
            bf.u2[0] = *(const uint2*)brp;
            bf.u2[1] = *(const uint2*)(brp + 4);
            a0 = __builtin_amdgcn_mfma_f32_16x16x32_bf16(af0, bf.v, a0, 0, 0, 0);
            a1 = __builtin_amdgcn_mfma_f32_16x16x32_bf16(af1, bf.v, a1, 0, 0, 0);
        }
        int col = n0 + (w << 4) + l15;
        float bv = b2[col];
        #pragma unroll
        for (int r = 0; r < 4; ++r) {
            int lr0 = (quad << 2) + r;
            if (lr0 < rows)
                atomicAdd(&accG[(size_t)tok[lr0] * D_DIM + col], wt[lr0] * (a0[r] + bv));
            int lr1 = 16 + lr0;
            if (lr1 < rows)
                atomicAdd(&accG[(size_t)tok[lr1] * D_DIM + col], wt[lr1] * (a1[r] + bv));
        }
    }
}

// ---------------- final: out = x + acc (all fp32) ----------------
__global__ __launch_bounds__(256) void final_k(
    const float* __restrict__ x, const float* __restrict__ acc, float* __restrict__ out)
{
    size_t i = ((size_t)blockIdx.x * 256 + threadIdx.x) << 2;
    float4 xv = *(const float4*)(x + i);
    float4 a = *(const float4*)(acc + i);
    float4 o;
    o.x = xv.x + a.x;
    o.y = xv.y + a.y;
    o.z = xv.z + a.z;
    o.w = xv.w + a.w;
    *(float4*)(out + i) = o;
}

extern "C" void kernel_launch(void* const* d_in, const int* in_sizes, int n_in,
                              void* d_out, int out_size, void* d_ws, size_t ws_size,
                              hipStream_t stream)
{
    const float* x     = (const float*)d_in[0];
    const float* nw    = (const float*)d_in[1];
    const float* Wr    = (const float*)d_in[2];
    const float* sW1   = (const float*)d_in[3];
    const float* sb1   = (const float*)d_in[4];
    const float* sW2   = (const float*)d_in[5];
    const float* sb2   = (const float*)d_in[6];
    const float* sWg   = (const float*)d_in[7];
    const float* rW1   = (const float*)d_in[8];
    const float* rb1   = (const float*)d_in[9];
    const float* rW2   = (const float*)d_in[10];
    const float* rb2   = (const float*)d_in[11];
    const float* rWg   = (const float*)d_in[12];
    const float* ebias = (const float*)d_in[13];
    float* out = (float*)d_out;
    (void)in_sizes; (void)n_in; (void)out_size;

    char* wp = (char*)d_ws;
    auto alloc = [&](size_t b) { char* p = wp; wp += (b + 255) & ~(size_t)255; return p; };
    int*   cnt  = (int*)alloc(N_EXP * 4);
    int*   offs = (int*)alloc((N_EXP + 1) * 4);
    int*   fill = (int*)alloc(N_EXP * 4);
    int*   tki  = (int*)alloc((size_t)T_TOK * K_TOP * 4);
    float* tkw  = (float*)alloc((size_t)T_TOK * K_TOP * 4);
    int*   atok = (int*)alloc((size_t)N_ASG * 4);
    float* aw   = (float*)alloc((size_t)N_ASG * 4);
    float* raw  = (float*)alloc((size_t)T_TOK * N_EXP * 4);
    u16*   xnb  = (u16*)alloc((size_t)T_TOK * D_DIM * 2);
    float* acc  = (float*)alloc((size_t)T_TOK * D_DIM * 4);
    // fast-path: bf16-transposed weights (~139.5 MB)
    u16* rW1t = (u16*)alloc((size_t)N_EXP * H_DIM * D_DIM * 2);
    u16* rW2t = (u16*)alloc((size_t)N_EXP * H_DIM * D_DIM * 2);
    u16* rWgt = (u16*)alloc((size_t)H_DIM * H_DIM * 2);
    u16* sW1t = (u16*)alloc((size_t)2 * H_DIM * D_DIM * 2);
    u16* sW2t = (u16*)alloc((size_t)2 * H_DIM * D_DIM * 2);
    u16* sWgt = (u16*)alloc((size_t)H_DIM * H_DIM * 2);
    bool fast = (size_t)(wp - (char*)d_ws) <= ws_size;

    hipMemsetAsync(cnt, 0, N_EXP * 4, stream);
    hipMemsetAsync(acc, 0, (size_t)T_TOK * D_DIM * 4, stream);

    dim3 b256(256);
    rmsnorm_k<<<T_TOK, b256, 0, stream>>>(x, nw, xnb);
    routernorm_k<<<T_TOK, b256, 0, stream>>>(x, nw, Wr, raw);
    topk_k<<<T_TOK, dim3(64), 0, stream>>>(raw, ebias, cnt, tki, tkw);
    scan_k<<<1, dim3(64), 0, stream>>>(cnt, offs, fill);
    fill_k<<<T_TOK, dim3(64), 0, stream>>>(tki, tkw, fill, atok, aw);

    if (fast) {
        // transpose+convert: in [K][N] fp32 -> out [N][K] bf16, grid (N/64, K/64, nmat)
        convT_k<<<dim3(H_DIM / 64, D_DIM / 64, N_EXP), b256, 0, stream>>>(rW1, rW1t, D_DIM, H_DIM);
        convT_k<<<dim3(D_DIM / 64, H_DIM / 64, N_EXP), b256, 0, stream>>>(rW2, rW2t, H_DIM, D_DIM);
        convT_k<<<dim3(H_DIM / 64, H_DIM / 64, 1), b256, 0, stream>>>(rWg, rWgt, H_DIM, H_DIM);
        convT_k<<<dim3(H_DIM / 64, D_DIM / 64, 2), b256, 0, stream>>>(sW1, sW1t, D_DIM, H_DIM);
        convT_k<<<dim3(D_DIM / 64, H_DIM / 64, 2), b256, 0, stream>>>(sW2, sW2t, H_DIM, D_DIM);
        convT_k<<<dim3(H_DIM / 64, H_DIM / 64, 1), b256, 0, stream>>>(sWg, sWgt, H_DIM, H_DIM);

        // grid (expert, slab): linear id % 8 == e % 8 -> expert->XCD L2 affinity
        moe_ffn2_k<1><<<dim3(N_EXP, 64, 1), b256, 0, stream>>>(
            xnb, rW1t, rWgt, rW2t, rb1, rb2, offs, atok, aw, acc);
        moe_ffn2_k<0><<<dim3(2, 64, 1), b256, 0, stream>>>(
            xnb, sW1t, sWgt, sW2t, sb1, sb2, offs, atok, aw, acc);
    } else {
        moe_ffn_k<1><<<dim3(1, 64, N_EXP), b256, 0, stream>>>(
            xnb, rW1, rWg, rW2, rb1, rb2, offs, atok, aw, acc);
        moe_ffn_k<0><<<dim3(1, 64, 2), b256, 0, stream>>>(
            xnb, sW1, sWg, sW2, sb1, sb2, offs, atok, aw, acc);
    }

    final_k<<<(T_TOK * D_DIM) / 1024, b256, 0, stream>>>(x, acc, out);
}

// Round 2
// 741.115 us; speedup vs baseline: 3.8336x; 1.2942x over previous
//
#include <hip/hip_runtime.h>
#include <cstdint>
#include <cstddef>

typedef unsigned short u16;
typedef unsigned int u32;
typedef __attribute__((ext_vector_type(8))) short bh8;
typedef __attribute__((ext_vector_type(4))) float fx4;

#define T_TOK 2048
#define D_DIM 1024
#define H_DIM 512
#define N_EXP 64
#define K_TOP 6
#define N_ASG (T_TOK * K_TOP)   // 12288

__device__ __forceinline__ float bf2f(u16 v) {
    union { u32 u; float f; } c; c.u = ((u32)v) << 16; return c.f;
}
__device__ __forceinline__ u16 f2bf(float f) {
    union { u32 u; float f; } c; c.f = f;
    u32 u = c.u;
    return (u16)((u + 0x7fffu + ((u >> 16) & 1u)) >> 16);
}

// ---------------- RMSNorm (f32 in) -> xnb (bf16) ----------------
__global__ __launch_bounds__(256) void rmsnorm_k(
    const float* __restrict__ x, const float* __restrict__ nw, u16* __restrict__ xnb)
{
    int t = blockIdx.x, tid = threadIdx.x;
    int d0 = tid << 2;
    float4 xv = *(const float4*)(x + (size_t)t * D_DIM + d0);
    float ss = xv.x * xv.x + xv.y * xv.y + xv.z * xv.z + xv.w * xv.w;
    #pragma unroll
    for (int o = 32; o > 0; o >>= 1) ss += __shfl_down(ss, o);
    __shared__ float red[4];
    if ((tid & 63) == 0) red[tid >> 6] = ss;
    __syncthreads();
    float ms = (red[0] + red[1] + red[2] + red[3]) * (1.f / (float)D_DIM);
    float sc = rsqrtf(ms + 1.1920929e-07f);
    float4 wv = *(const float4*)(nw + d0);
    ushort4 ob;
    ob.x = f2bf(xv.x * sc * wv.x);
    ob.y = f2bf(xv.y * sc * wv.y);
    ob.z = f2bf(xv.z * sc * wv.z);
    ob.w = f2bf(xv.w * sc * wv.w);
    *(ushort4*)(xnb + (size_t)t * D_DIM + d0) = ob;
}

// ---------------- router with fused fp32 norm: raw[t][e] (all fp32) ----------------
__global__ __launch_bounds__(256) void routernorm_k(
    const float* __restrict__ x, const float* __restrict__ nw,
    const float* __restrict__ Wr, float* __restrict__ raw)
{
    int t = blockIdx.x, tid = threadIdx.x;
    __shared__ float xs[D_DIM];
    __shared__ float ps[256];
    __shared__ float red[4];
    int d0 = tid << 2;
    float4 xv = *(const float4*)(x + (size_t)t * D_DIM + d0);
    float ss = xv.x * xv.x + xv.y * xv.y + xv.z * xv.z + xv.w * xv.w;
    #pragma unroll
    for (int o = 32; o > 0; o >>= 1) ss += __shfl_down(ss, o);
    if ((tid & 63) == 0) red[tid >> 6] = ss;
    __syncthreads();
    float ms = (red[0] + red[1] + red[2] + red[3]) * (1.f / (float)D_DIM);
    float sc = rsqrtf(ms + 1.1920929e-07f);
    float4 wv = *(const float4*)(nw + d0);
    float4 xf;
    xf.x = xv.x * sc * wv.x;
    xf.y = xv.y * sc * wv.y;
    xf.z = xv.z * sc * wv.z;
    xf.w = xv.w * sc * wv.w;
    *(float4*)&xs[d0] = xf;
    __syncthreads();
    int e = tid & 63, part = tid >> 6;
    const float* wr = Wr + (size_t)e * D_DIM + part * 256;
    const float* xp = &xs[part * 256];
    float s = 0.f;
    #pragma unroll 8
    for (int i = 0; i < 256; i += 4) {
        float4 w4 = *(const float4*)(wr + i);
        s += xp[i] * w4.x + xp[i + 1] * w4.y + xp[i + 2] * w4.z + xp[i + 3] * w4.w;
    }
    ps[tid] = s;
    __syncthreads();
    if (part == 0) raw[(size_t)t * N_EXP + e] = ps[e] + ps[64 + e] + ps[128 + e] + ps[192 + e];
}

// ---------------- top-k (one wave per token), fp32 ----------------
__global__ void topk_k(const float* __restrict__ raw, const float* __restrict__ ebias,
                       int* __restrict__ cnt, int* __restrict__ tki, float* __restrict__ tkw)
{
    int t = blockIdx.x, lane = threadIdx.x;
    float r = raw[(size_t)t * N_EXP + lane];
    float cur = r + ebias[lane];
    int selI[K_TOP]; float selR[K_TOP];
    #pragma unroll
    for (int k = 0; k < K_TOP; ++k) {
        float v = cur; int id = lane;
        #pragma unroll
        for (int o = 32; o > 0; o >>= 1) {
            float v2 = __shfl_down(v, o); int i2 = __shfl_down(id, o);
            if (v2 > v || (v2 == v && i2 < id)) { v = v2; id = i2; }
        }
        id = __shfl(id, 0);
        if (lane == id) cur = -3.4e38f;
        selI[k] = id;
        selR[k] = __shfl(r, id);
    }
    float s = 0.f;
    #pragma unroll
    for (int k = 0; k < K_TOP; ++k) s += selR[k];
    if (lane < K_TOP) {
        tki[t * K_TOP + lane] = selI[lane];
        tkw[t * K_TOP + lane] = selR[lane] / s;
        atomicAdd(&cnt[selI[lane]], 1);
    }
}

__global__ void scan_k(const int* __restrict__ cnt, int* __restrict__ offs, int* __restrict__ fill)
{
    if (threadIdx.x == 0) {
        int s = 0;
        for (int e = 0; e < N_EXP; ++e) { offs[e] = s; fill[e] = s; s += cnt[e]; }
        offs[N_EXP] = s;
    }
}

__global__ void fill_k(const int* __restrict__ tki, const float* __restrict__ tkw,
                       int* __restrict__ fill, int* __restrict__ atok, float* __restrict__ aw)
{
    int t = blockIdx.x, lane = threadIdx.x;
    if (lane < K_TOP) {
        int e = tki[t * K_TOP + lane];
        int p = atomicAdd(&fill[e], 1);
        atok[p] = t;
        aw[p] = tkw[t * K_TOP + lane];
    }
}

// ---------------- weight convert to MFMA-fragment-packed bf16 ----------------
// in: fp32 [mat][K][N]. out: per mat, frag(n_tile, kb) of 1KB:
//   offset_u16 = (n_tile*(K/32) + kb)*512 + lane*8;  element j of lane l =
//   W[ kb*32 + (l>>4)*8 + j ][ n_tile*16 + (l&15) ]   (i.e. B-operand layout)
// grid: (N/64, K/64, nmat), 256 threads
__global__ __launch_bounds__(256) void convF_k(
    const float* __restrict__ in, u16* __restrict__ out, int K, int N)
{
    int mat = blockIdx.z;
    size_t mo = (size_t)mat * K * N;
    int n0 = blockIdx.x << 6, k0 = blockIdx.y << 6;
    __shared__ u16 t[64][72];          // [n_local][k_local]
    int tid = threadIdx.x;
    int kr = tid >> 4, c4 = (tid & 15) << 2;
    #pragma unroll
    for (int rr = 0; rr < 4; ++rr) {
        int k = (rr << 4) + kr;
        float4 v = *(const float4*)(in + mo + (size_t)(k0 + k) * N + n0 + c4);
        t[c4 + 0][k] = f2bf(v.x);
        t[c4 + 1][k] = f2bf(v.y);
        t[c4 + 2][k] = f2bf(v.z);
        t[c4 + 3][k] = f2bf(v.w);
    }
    __syncthreads();
    int lane = tid & 63, g = tid >> 6;
    int nr = lane & 15, kq = lane >> 4;
    #pragma unroll
    for (int f = 0; f < 2; ++f) {
        int fragId = g + (f << 2);                 // 0..7 = (n_tile 0..3) x (kb 0..1)
        int ntile = fragId >> 1, kb = fragId & 1;
        bh8 v = *(const bh8*)&t[(ntile << 4) + nr][(kb << 5) + (kq << 3)];
        size_t fi = (((size_t)((n0 >> 4) + ntile) * (size_t)(K >> 5)
                      + (size_t)((k0 >> 5) + kb)) << 9) + (size_t)(lane << 3);
        *(bh8*)(out + mo + fi) = v;
    }
}

// ============ merged fused FFN: experts 0..63 routed, 64..65 shared ============
// 32-row slab, 256 threads = 4 waves; wave w owns a 128-col panel.
// B loads are frag-packed: 1KB coalesced bursts, contiguous streaming over kb.
// A rows staged once into LDS (overlaying hA/hG, dead at that point).
__global__ __launch_bounds__(256) void moe_ffn3_k(
    const u16* __restrict__ xnb,
    const u16* __restrict__ W1f,   // [66][frag-packed 512x1024]
    const u16* __restrict__ Wgf,   // [2][frag-packed 512x512] (0=routed,1=shared)
    const u16* __restrict__ W2f,   // [66][frag-packed 1024x512]
    const float* __restrict__ rb1, const float* __restrict__ rb2,
    const float* __restrict__ sb1, const float* __restrict__ sb2,
    const int* __restrict__ offs, const int* __restrict__ atok,
    const float* __restrict__ aw, float* __restrict__ accG)
{
    int e = blockIdx.x;
    bool routed = e < N_EXP;
    int start = routed ? offs[e] : 0;
    int end   = routed ? offs[e + 1] : T_TOK;
    int rowBase = start + (blockIdx.y << 5);
    if (rowBase >= end) return;
    int rows = end - rowBase; if (rows > 32) rows = 32;

    __shared__ int   tok[32];
    __shared__ float wt[32];
    __shared__ u16 hbuf[33280];        // hA | hG ; phase-1 A-stage overlays all of it
    u16* hA = hbuf;
    u16* hG = hbuf + 16640;

    int tid = threadIdx.x;
    if (tid < 32) {
        int cl = rowBase + tid; if (cl >= end) cl = end - 1;
        tok[tid] = routed ? atok[cl] : cl;
        wt[tid]  = routed ? aw[cl] : 1.0f;
    }
    __syncthreads();

    // ---- stage A: 32 token rows (bf16, 1024 each) into Ast (pitch 1032) ----
    {
        u16* Ast = hbuf;
        #pragma unroll
        for (int p = 0; p < 16; ++p) {
            int r = (p << 1) + (tid >> 7);
            int c = (tid & 127) << 3;
            *(uint4*)&Ast[r * 1032 + c] = *(const uint4*)(xnb + (size_t)tok[r] * D_DIM + c);
        }
    }
    __syncthreads();

    int w = tid >> 6, lane = tid & 63, quad = lane >> 4, l15 = lane & 15;
    int n0w = w << 7;

    const u16* W1e = W1f + (size_t)e * (H_DIM * D_DIM);
    const u16* W2e = W2f + (size_t)e * (H_DIM * D_DIM);
    const u16* Wge = Wgf + (routed ? 0 : (size_t)(H_DIM * H_DIM));
    const float* b1 = routed ? rb1 + e * H_DIM : sb1 + (e - N_EXP) * H_DIM;
    const float* b2 = routed ? rb2 + e * D_DIM : sb2 + (e - N_EXP) * D_DIM;

    // ---- phase 1: h = xn @ W1 + b1 (K=1024 -> N=512) ----
    {
        const u16* Ast = hbuf;
        const u16* bp = W1e + ((size_t)w << 17) + (lane << 3);   // w*8 tiles * 32 kb * 512
        fx4 ac0[8] = {}, ac1[8] = {};
        #pragma unroll 2
        for (int kbi = 0; kbi < 32; ++kbi) {
            bh8 a0 = *(const bh8*)&Ast[l15 * 1032 + (kbi << 5) + (quad << 3)];
            bh8 a1 = *(const bh8*)&Ast[(16 + l15) * 1032 + (kbi << 5) + (quad << 3)];
            #pragma unroll
            for (int ct = 0; ct < 8; ++ct) {
                bh8 b = *(const bh8*)(bp + (((ct << 5) + kbi) << 9));
                ac0[ct] = __builtin_amdgcn_mfma_f32_16x16x32_bf16(a0, b, ac0[ct], 0, 0, 0);
                ac1[ct] = __builtin_amdgcn_mfma_f32_16x16x32_bf16(a1, b, ac1[ct], 0, 0, 0);
            }
        }
        __syncthreads();   // Ast dead; safe to overwrite with hA
        #pragma unroll
        for (int ct = 0; ct < 8; ++ct) {
            int col = n0w + (ct << 4) + l15;
            float bv = b1[col];
            #pragma unroll
            for (int r = 0; r < 4; ++r) {
                int r0 = (quad << 2) + r;
                hA[r0 * 520 + col]        = f2bf(ac0[ct][r] + bv);
                hA[(16 + r0) * 520 + col] = f2bf(ac1[ct][r] + bv);
            }
        }
    }
    __syncthreads();

    // ---- phase 2: hg = h * silu(h @ Wg) (K=512 -> N=512) ----
    {
        const u16* bp = Wge + ((size_t)w << 16) + (lane << 3);   // w*8 tiles * 16 kb * 512
        fx4 ac0[8] = {}, ac1[8] = {};
        #pragma unroll 2
        for (int kbi = 0; kbi < 16; ++kbi) {
            bh8 a0 = *(const bh8*)&hA[l15 * 520 + (kbi << 5) + (quad << 3)];
            bh8 a1 = *(const bh8*)&hA[(16 + l15) * 520 + (kbi << 5) + (quad << 3)];
            #pragma unroll
            for (int ct = 0; ct < 8; ++ct) {
                bh8 b = *(const bh8*)(bp + (((ct << 4) + kbi) << 9));
                ac0[ct] = __builtin_amdgcn_mfma_f32_16x16x32_bf16(a0, b, ac0[ct], 0, 0, 0);
                ac1[ct] = __builtin_amdgcn_mfma_f32_16x16x32_bf16(a1, b, ac1[ct], 0, 0, 0);
            }
        }
        #pragma unroll
        for (int ct = 0; ct < 8; ++ct) {
            int col = n0w + (ct << 4) + l15;
            #pragma unroll
            for (int r = 0; r < 4; ++r) {
                int r0 = (quad << 2) + r;
                float g0 = ac0[ct][r];
                float h0 = bf2f(hA[r0 * 520 + col]);
                hG[r0 * 520 + col] = f2bf(h0 * g0 * (1.f / (1.f + __expf(-g0))));
                int r1 = 16 + r0;
                float g1 = ac1[ct][r];
                float h1 = bf2f(hA[r1 * 520 + col]);
                hG[r1 * 520 + col] = f2bf(h1 * g1 * (1.f / (1.f + __expf(-g1))));
            }
        }
    }
    __syncthreads();

    // ---- phase 3: acc[tok] += wt * (hg @ W2 + b2) (K=512 -> N=1024, 2 halves/wave) ----
    #pragma unroll 1
    for (int half = 0; half < 2; ++half) {
        int n0 = (w << 8) + (half << 7);
        const u16* bp = W2e + (((size_t)((w << 4) + (half << 3))) << 13) + (lane << 3);
        fx4 ac0[8] = {}, ac1[8] = {};
        #pragma unroll 2
        for (int kbi = 0; kbi < 16; ++kbi) {
            bh8 a0 = *(const bh8*)&hG[l15 * 520 + (kbi << 5) + (quad << 3)];
            bh8 a1 = *(const bh8*)&hG[(16 + l15) * 520 + (kbi << 5) + (quad << 3)];
            #pragma unroll
            for (int ct = 0; ct < 8; ++ct) {
                bh8 b = *(const bh8*)(bp + (((ct << 4) + kbi) << 9));
                ac0[ct] = __builtin_amdgcn_mfma_f32_16x16x32_bf16(a0, b, ac0[ct], 0, 0, 0);
                ac1[ct] = __builtin_amdgcn_mfma_f32_16x16x32_bf16(a1, b, ac1[ct], 0, 0, 0);
            }
        }
        #pragma unroll
        for (int ct = 0; ct < 8; ++ct) {
            int col = n0 + (ct << 4) + l15;
            float bv = b2[col];
            #pragma unroll
            for (int r = 0; r < 4; ++r) {
                int r0 = (quad << 2) + r;
                if (r0 < rows)
                    atomicAdd(&accG[(size_t)tok[r0] * D_DIM + col], wt[r0] * (ac0[ct][r] + bv));
                int r1 = 16 + r0;
                if (r1 < rows)
                    atomicAdd(&accG[(size_t)tok[r1] * D_DIM + col], wt[r1] * (ac1[ct][r] + bv));
            }
        }
    }
}

// ============ fallback fused FFN (raw fp32 weights), used only if workspace too small ============
template<int ROUTED>
__global__ __launch_bounds__(256) void moe_ffn_k(
    const u16* __restrict__ xnb,
    const float* __restrict__ W1b, const float* __restrict__ Wg,
    const float* __restrict__ W2b,
    const float* __restrict__ b1b, const float* __restrict__ b2b,
    const int* __restrict__ offs, const int* __restrict__ atok,
    const float* __restrict__ aw, float* __restrict__ accG)
{
    int e = blockIdx.z;
    int start = ROUTED ? offs[e] : 0;
    int end   = ROUTED ? offs[e + 1] : T_TOK;
    int rowBase = start + (blockIdx.y << 5);
    if (rowBase >= end) return;
    int rows = end - rowBase; if (rows > 32) rows = 32;

    __shared__ int   tok[32];
    __shared__ float wt[32];
    __shared__ u16 hA[32 * 520];
    __shared__ u16 hG[32 * 520];
    __shared__ u16 As[32 * 32];
    __shared__ u16 Bs[64 * 36];

    int tid = threadIdx.x;
    if (tid < 32) {
        int cl = rowBase + tid; if (cl >= end) cl = end - 1;
        tok[tid] = ROUTED ? atok[cl] : cl;
        wt[tid]  = ROUTED ? aw[cl] : 1.0f;
    }
    __syncthreads();

    const float* W1 = W1b + (size_t)e * (D_DIM * H_DIM);
    const float* W2 = W2b + (size_t)e * (D_DIM * H_DIM);
    const float* b1 = b1b + e * H_DIM;
    const float* b2 = b2b + e * D_DIM;

    int w = tid >> 6, lane = tid & 63, quad = lane >> 4, l15 = lane & 15;
    int sr2 = tid >> 3, sc2 = (tid & 7) << 2;

    for (int nc = 0; nc < 8; ++nc) {
        int n0 = nc << 6;
        fx4 a0 = {}; fx4 a1 = {};
        for (int kc = 0; kc < 32; ++kc) {
            int kb = kc << 5;
            int2 av = *(const int2*)(xnb + (size_t)tok[sr2] * D_DIM + kb + sc2);
            const float* cp = W1 + n0 + lane;
            int kx = kb + (w << 3);
            u32 p[4];
            #pragma unroll
            for (int jj = 0; jj < 4; ++jj) {
                u32 lo = f2bf(cp[(size_t)(kx + 2 * jj) * H_DIM]);
                u32 hi = f2bf(cp[(size_t)(kx + 2 * jj + 1) * H_DIM]);
                p[jj] = lo | (hi << 16);
            }
            __syncthreads();
            *(int2*)&As[sr2 * 32 + sc2] = av;
            u16* bsw = &Bs[lane * 36 + (w << 3)];
            uint2 q0; q0.x = p[0]; q0.y = p[1];
            uint2 q1; q1.x = p[2]; q1.y = p[3];
            *(uint2*)bsw = q0;
            *(uint2*)(bsw + 4) = q1;
            __syncthreads();
            bh8 af0 = *(const bh8*)&As[l15 * 32 + (quad << 3)];
            bh8 af1 = *(const bh8*)&As[(16 + l15) * 32 + (quad << 3)];
            const u16* brp = &Bs[((w << 4) + l15) * 36 + (quad << 3)];
            union { bh8 v; uint2 u2[2]; } bf;
            bf.u2[0] = *(const uint2*)brp;
            bf.u2[1] = *(const uint2*)(brp + 4);
            a0 = __builtin_amdgcn_mfma_f32_16x16x32_bf16(af0, bf.v, a0, 0, 0, 0);
            a1 = __builtin_amdgcn_mfma_f32_16x16x32_bf16(af1, bf.v, a1, 0, 0, 0);
        }
        int col = n0 + (w << 4) + l15;
        float bv = b1[col];
        #pragma unroll
        for (int r = 0; r < 4; ++r) {
            hA[((quad << 2) + r) * 520 + col]      = f2bf(a0[r] + bv);
            hA[(16 + (quad << 2) + r) * 520 + col] = f2bf(a1[r] + bv);
        }
    }
    __syncthreads();

    for (int nc = 0; nc < 8; ++nc) {
        int n0 = nc << 6;
        fx4 a0 = {}; fx4 a1 = {};
        for (int kc = 0; kc < 16; ++kc) {
            int kb = kc << 5;
            const float* cp = Wg + n0 + lane;
            int kx = kb + (w << 3);
            u32 p[4];
            #pragma unroll
            for (int jj = 0; jj < 4; ++jj) {
                u32 lo = f2bf(cp[(size_t)(kx + 2 * jj) * H_DIM]);
                u32 hi = f2bf(cp[(size_t)(kx + 2 * jj + 1) * H_DIM]);
                p[jj] = lo | (hi << 16);
            }
            __syncthreads();
            u16* bsw = &Bs[lane * 36 + (w << 3)];
            uint2 q0; q0.x = p[0]; q0.y = p[1];
            uint2 q1; q1.x = p[2]; q1.y = p[3];
            *(uint2*)bsw = q0;
            *(uint2*)(bsw + 4) = q1;
            __syncthreads();
            bh8 af0 = *(const bh8*)&hA[l15 * 520 + kb + (quad << 3)];
            bh8 af1 = *(const bh8*)&hA[(16 + l15) * 520 + kb + (quad << 3)];
            const u16* brp = &Bs[((w << 4) + l15) * 36 + (quad << 3)];
            union { bh8 v; uint2 u2[2]; } bf;
            bf.u2[0] = *(const uint2*)brp;
            bf.u2[1] = *(const uint2*)(brp + 4);
            a0 = __builtin_amdgcn_mfma_f32_16x16x32_bf16(af0, bf.v, a0, 0, 0, 0);
            a1 = __builtin_amdgcn_mfma_f32_16x16x32_bf16(af1, bf.v, a1, 0, 0, 0);
        }
        int col = n0 + (w << 4) + l15;
        #pragma unroll
        for (int r = 0; r < 4; ++r) {
            int r0 = (quad << 2) + r;
            float h0 = bf2f(hA[r0 * 520 + col]);
            float g0 = a0[r];
            hG[r0 * 520 + col] = f2bf(h0 * g0 * (1.f / (1.f + __expf(-g0))));
            int r1 = 16 + r0;
            float h1 = bf2f(hA[r1 * 520 + col]);
            float g1 = a1[r];
            hG[r1 * 520 + col] = f2bf(h1 * g1 * (1.f / (1.f + __expf(-g1))));
        }
    }
    __syncthreads();

    for (int nc = 0; nc < 16; ++nc) {
        int n0 = nc << 6;
        fx4 a0 = {}; fx4 a1 = {};
        for (int kc = 0; kc < 16; ++kc) {
            int kb = kc << 5;
            const float* cp = W2 + n0 + lane;
            int kx = kb + (w << 3);
            u32 p[4];
            #pragma unroll
            for (int jj = 0; jj < 4; ++jj) {
                u32 lo = f2bf(cp[(size_t)(kx + 2 * jj) * D_DIM]);
                u32 hi = f2bf(cp[(size_t)(kx + 2 * jj + 1) * D_DIM]);
                p[jj] = lo | (hi << 16);
            }
            __syncthreads();
            u16* bsw = &Bs[lane * 36 + (w << 3)];
            uint2 q0; q0.x = p[0]; q0.y = p[1];
            uint2 q1; q1.x = p[2]; q1.y = p[3];
            *(uint2*)bsw = q0;
            *(uint2*)(bsw + 4) = q1;
            __syncthreads();
            bh8 af0 = *(const bh8*)&hG[l15 * 520 + kb + (quad << 3)];
            bh8 af1 = *(const bh8*)&hG[(16 + l15) * 520 + kb + (quad << 3)];
            const u16* brp = &Bs[((w << 4) + l15) * 36 + (quad << 3)];
            union { bh8 v; uint2 u2[2]; } bf;
            bf.u2[0] = *(const uint2*)brp;
            bf.u2[1] = *(const uint2*)(brp + 4);
            a0 = __builtin_amdgcn_mfma_f32_16x16x32_bf16(af0, bf.v, a0, 0, 0, 0);
            a1 = __builtin_amdgcn_mfma_f32_16x16x32_bf16(af1, bf.v, a1, 0, 0, 0);
        }
        int col = n0 + (w << 4) + l15;
        float bv = b2[col];
        #pragma unroll
        for (int r = 0; r < 4; ++r) {
            int lr0 = (quad << 2) + r;
            if (lr0 < rows)
                atomicAdd(&accG[(size_t)tok[lr0] * D_DIM + col], wt[lr0] * (a0[r] + bv));
            int lr1 = 16 + lr0;
            if (lr1 < rows)
                atomicAdd(&accG[(size_t)tok[lr1] * D_DIM + col], wt[lr1] * (a1[r] + bv));
        }
    }
}

// ---------------- final: out = x + acc (all fp32) ----------------
__global__ __launch_bounds__(256) void final_k(
    const float* __restrict__ x, const float* __restrict__ acc, float* __restrict__ out)
{
    size_t i = ((size_t)blockIdx.x * 256 + threadIdx.x) << 2;
    float4 xv = *(const float4*)(x + i);
    float4 a = *(const float4*)(acc + i);
    float4 o;
    o.x = xv.x + a.x;
    o.y = xv.y + a.y;
    o.z = xv.z + a.z;
    o.w = xv.w + a.w;
    *(float4*)(out + i) = o;
}

extern "C" void kernel_launch(void* const* d_in, const int* in_sizes, int n_in,
                              void* d_out, int out_size, void* d_ws, size_t ws_size,
                              hipStream_t stream)
{
    const float* x     = (const float*)d_in[0];
    const float* nw    = (const float*)d_in[1];
    const float* Wr    = (const float*)d_in[2];
    const float* sW1   = (const float*)d_in[3];
    const float* sb1   = (const float*)d_in[4];
    const float* sW2   = (const float*)d_in[5];
    const float* sb2   = (const float*)d_in[6];
    const float* sWg   = (const float*)d_in[7];
    const float* rW1   = (const float*)d_in[8];
    const float* rb1   = (const float*)d_in[9];
    const float* rW2   = (const float*)d_in[10];
    const float* rb2   = (const float*)d_in[11];
    const float* rWg   = (const float*)d_in[12];
    const float* ebias = (const float*)d_in[13];
    float* out = (float*)d_out;
    (void)in_sizes; (void)n_in; (void)out_size;

    char* wp = (char*)d_ws;
    auto alloc = [&](size_t b) { char* p = wp; wp += (b + 255) & ~(size_t)255; return p; };
    int*   cnt  = (int*)alloc(N_EXP * 4);
    int*   offs = (int*)alloc((N_EXP + 1) * 4);
    int*   fill = (int*)alloc(N_EXP * 4);
    int*   tki  = (int*)alloc((size_t)T_TOK * K_TOP * 4);
    float* tkw  = (float*)alloc((size_t)T_TOK * K_TOP * 4);
    int*   atok = (int*)alloc((size_t)N_ASG * 4);
    float* aw   = (float*)alloc((size_t)N_ASG * 4);
    float* raw  = (float*)alloc((size_t)T_TOK * N_EXP * 4);
    u16*   xnb  = (u16*)alloc((size_t)T_TOK * D_DIM * 2);
    float* acc  = (float*)alloc((size_t)T_TOK * D_DIM * 4);
    // fast-path: fragment-packed bf16 weights, 66 experts (64 routed + 2 shared)
    u16* W1f = (u16*)alloc((size_t)(N_EXP + 2) * H_DIM * D_DIM * 2);
    u16* W2f = (u16*)alloc((size_t)(N_EXP + 2) * H_DIM * D_DIM * 2);
    u16* Wgf = (u16*)alloc((size_t)2 * H_DIM * H_DIM * 2);
    bool fast = (size_t)(wp - (char*)d_ws) <= ws_size;

    hipMemsetAsync(cnt, 0, N_EXP * 4, stream);
    hipMemsetAsync(acc, 0, (size_t)T_TOK * D_DIM * 4, stream);

    dim3 b256(256);
    rmsnorm_k<<<T_TOK, b256, 0, stream>>>(x, nw, xnb);
    routernorm_k<<<T_TOK, b256, 0, stream>>>(x, nw, Wr, raw);
    topk_k<<<T_TOK, dim3(64), 0, stream>>>(raw, ebias, cnt, tki, tkw);
    scan_k<<<1, dim3(64), 0, stream>>>(cnt, offs, fill);
    fill_k<<<T_TOK, dim3(64), 0, stream>>>(tki, tkw, fill, atok, aw);

    if (fast) {
        size_t ms = (size_t)H_DIM * D_DIM;
        // W1: in [K=1024][N=512]
        convF_k<<<dim3(H_DIM / 64, D_DIM / 64, N_EXP), b256, 0, stream>>>(rW1, W1f, D_DIM, H_DIM);
        convF_k<<<dim3(H_DIM / 64, D_DIM / 64, 2), b256, 0, stream>>>(sW1, W1f + (size_t)N_EXP * ms, D_DIM, H_DIM);
        // W2: in [K=512][N=1024]
        convF_k<<<dim3(D_DIM / 64, H_DIM / 64, N_EXP), b256, 0, stream>>>(rW2, W2f, H_DIM, D_DIM);
        convF_k<<<dim3(D_DIM / 64, H_DIM / 64, 2), b256, 0, stream>>>(sW2, W2f + (size_t)N_EXP * ms, H_DIM, D_DIM);
        // Wg: in [512][512]
        convF_k<<<dim3(H_DIM / 64, H_DIM / 64, 1), b256, 0, stream>>>(rWg, Wgf, H_DIM, H_DIM);
        convF_k<<<dim3(H_DIM / 64, H_DIM / 64, 1), b256, 0, stream>>>(sWg, Wgf + (size_t)H_DIM * H_DIM, H_DIM, H_DIM);

        moe_ffn3_k<<<dim3(N_EXP + 2, 64, 1), b256, 0, stream>>>(
            xnb, W1f, Wgf, W2f, rb1, rb2, sb1, sb2, offs, atok, aw, acc);
    } else {
        moe_ffn_k<1><<<dim3(1, 64, N_EXP), b256, 0, stream>>>(
            xnb, rW1, rWg, rW2, rb1, rb2, offs, atok, aw, acc);
        moe_ffn_k<0><<<dim3(1, 64, 2), b256, 0, stream>>>(
            xnb, sW1, sWg, sW2, sb1, sb2, offs, atok, aw, acc);
    }

    final_k<<<(T_TOK * D_DIM) / 1024, b256, 0, stream>>>(x, acc, out);
}